// Round 1
// baseline (1066.379 us; speedup 1.0000x reference)
//
#include <hip/hip_runtime.h>

// Problem constants (fixed by reference)
#define HDIM 256
constexpr int N_SRC = 131072, N_MID = 32768, N_DST = 8192;
constexpr int E1 = 524288, E2 = 131072;
constexpr int N_PAIRS = 8192;

// ---------------------------------------------------------------------------
// Generic fp32 GEMM: C[M,N] = act( beta*C + A[M,K] @ B[N,K]^T + bias[N] )
// A row-major lda, B row-major ldb (weights stored [N,K]), C row-major ldc.
// 128x128 tile, BK=16, 256 threads, 8x8 per thread (2x2 quadrant layout).
// All M multiples of 128, N=256 (grid.y=2), K=256.
// ---------------------------------------------------------------------------
template<int ACT, int BETA, int BIAS>
__global__ __launch_bounds__(256)
void gemm_tn(const float* __restrict__ A, int lda,
             const float* __restrict__ B, int ldb,
             const float* __restrict__ bias,
             float* __restrict__ C, int ldc,
             int K)
{
    __shared__ float As[16][132];
    __shared__ float Bs[16][132];
    const int bm = blockIdx.x * 128;
    const int bn = blockIdx.y * 128;
    const int t  = threadIdx.x;
    const int tx = t & 15, ty = t >> 4;

    float acc[8][8];
#pragma unroll
    for (int i = 0; i < 8; ++i)
#pragma unroll
        for (int j = 0; j < 8; ++j) acc[i][j] = 0.f;

    const int lrow0 = t >> 2;        // 0..63
    const int lc4   = (t & 3) << 2;  // 0,4,8,12

    for (int k0 = 0; k0 < K; k0 += 16) {
#pragma unroll
        for (int l = 0; l < 2; ++l) {
            const int row = lrow0 + l * 64;
            const float4 av = *reinterpret_cast<const float4*>(
                &A[(size_t)(bm + row) * lda + (k0 + lc4)]);
            As[lc4 + 0][row] = av.x; As[lc4 + 1][row] = av.y;
            As[lc4 + 2][row] = av.z; As[lc4 + 3][row] = av.w;
            const float4 bv = *reinterpret_cast<const float4*>(
                &B[(size_t)(bn + row) * ldb + (k0 + lc4)]);
            Bs[lc4 + 0][row] = bv.x; Bs[lc4 + 1][row] = bv.y;
            Bs[lc4 + 2][row] = bv.z; Bs[lc4 + 3][row] = bv.w;
        }
        __syncthreads();
#pragma unroll
        for (int k = 0; k < 16; ++k) {
            float a[8], b[8];
#pragma unroll
            for (int i = 0; i < 4; ++i) {
                a[i]     = As[k][ty * 4 + i];
                a[i + 4] = As[k][64 + ty * 4 + i];
                b[i]     = Bs[k][tx * 4 + i];
                b[i + 4] = Bs[k][64 + tx * 4 + i];
            }
#pragma unroll
            for (int i = 0; i < 8; ++i)
#pragma unroll
                for (int j = 0; j < 8; ++j)
                    acc[i][j] += a[i] * b[j];
        }
        __syncthreads();
    }

#pragma unroll
    for (int i = 0; i < 8; ++i) {
        const int m = bm + (i < 4 ? ty * 4 + i : 64 + ty * 4 + (i - 4));
#pragma unroll
        for (int jj = 0; jj < 2; ++jj) {
            const int n = bn + jj * 64 + tx * 4;
            float4 v;
            v.x = acc[i][jj * 4 + 0]; v.y = acc[i][jj * 4 + 1];
            v.z = acc[i][jj * 4 + 2]; v.w = acc[i][jj * 4 + 3];
            float* cp = &C[(size_t)m * ldc + n];
            if (BETA) {
                const float4 c0 = *reinterpret_cast<const float4*>(cp);
                v.x += c0.x; v.y += c0.y; v.z += c0.z; v.w += c0.w;
            }
            if (BIAS) {
                v.x += bias[n + 0]; v.y += bias[n + 1];
                v.z += bias[n + 2]; v.w += bias[n + 3];
            }
            if (ACT) {
                v.x = fmaxf(v.x, 0.f); v.y = fmaxf(v.y, 0.f);
                v.z = fmaxf(v.z, 0.f); v.w = fmaxf(v.w, 0.f);
            }
            *reinterpret_cast<float4*>(cp) = v;
        }
    }
}

// ---------------------------------------------------------------------------
// CSR build: count -> scan -> fill  (counting sort of edges by dst)
// ---------------------------------------------------------------------------
__global__ void edge_count(const int* __restrict__ dst, int E, int* __restrict__ counts)
{
    int i = blockIdx.x * blockDim.x + threadIdx.x;
    const int stride = gridDim.x * blockDim.x;
    for (; i < E; i += stride) atomicAdd(&counts[dst[i]], 1);
}

__global__ __launch_bounds__(1024)
void scan_kernel(const int* __restrict__ counts, int n,
                 int* __restrict__ row_start, int* __restrict__ cursor)
{
    __shared__ int part[1024];
    const int t = threadIdx.x;
    const int per = n >> 10;          // n is a multiple of 1024
    const int base = t * per;
    int s = 0;
    for (int j = 0; j < per; ++j) s += counts[base + j];
    part[t] = s;
    __syncthreads();
    for (int off = 1; off < 1024; off <<= 1) {
        int v = (t >= off) ? part[t - off] : 0;
        __syncthreads();
        part[t] += v;
        __syncthreads();
    }
    int run = (t == 0) ? 0 : part[t - 1];  // exclusive prefix
    for (int j = 0; j < per; ++j) {
        row_start[base + j] = run;
        cursor[base + j] = run;
        run += counts[base + j];
    }
    if (t == 1023) row_start[n] = run;
}

__global__ void edge_fill(const int* __restrict__ dst, int E,
                          int* __restrict__ cursor, int* __restrict__ elist)
{
    int i = blockIdx.x * blockDim.x + threadIdx.x;
    const int stride = gridDim.x * blockDim.x;
    for (; i < E; i += stride) {
        const int p = atomicAdd(&cursor[dst[i]], 1);
        elist[p] = i;
    }
}

// ---------------------------------------------------------------------------
// Weighted aggregate (normalized): aggn[d,:] = sum_e w_e * nsrc[src_e,:] / max(sum w,1)
// One block (256 threads = H) per dst node; CSR edge list.
// ---------------------------------------------------------------------------
__global__ __launch_bounds__(256)
void aggregate(const float* __restrict__ nsrc, const int* __restrict__ src,
               const float* __restrict__ w, const int* __restrict__ rs,
               const int* __restrict__ el, float* __restrict__ aggn)
{
    const int d = blockIdx.x, t = threadIdx.x;
    const int p0 = rs[d], p1 = rs[d + 1];
    float acc = 0.f, wsum = 0.f;
    for (int p = p0; p < p1; ++p) {
        const int e = el[p];
        const float wt = w[e];
        const int s = src[e];
        acc  += nsrc[(size_t)s * HDIM + t] * wt;
        wsum += wt;
    }
    aggn[(size_t)d * HDIM + t] = acc / fmaxf(wsum, 1.0f);
}

// ---------------------------------------------------------------------------
// z = hp[:N_DST] + h2; L2-normalize rows
// ---------------------------------------------------------------------------
__global__ __launch_bounds__(256)
void skip_norm(const float* __restrict__ hp, const float* __restrict__ h2,
               float* __restrict__ z)
{
    __shared__ float sm[4];
    const int d = blockIdx.x, t = threadIdx.x;
    const float v = hp[(size_t)d * HDIM + t] + h2[(size_t)d * HDIM + t];
    float s = v * v;
#pragma unroll
    for (int off = 32; off > 0; off >>= 1) s += __shfl_down(s, off);
    if ((t & 63) == 0) sm[t >> 6] = s;
    __syncthreads();
    const float tot = sm[0] + sm[1] + sm[2] + sm[3];
    const float nrm = sqrtf(tot);
    const float inv = (nrm == 0.f) ? 1.f : 1.f / nrm;
    z[(size_t)d * HDIM + t] = v * inv;
}

// ---------------------------------------------------------------------------
// out[p] = max( (dot(z[ns],z[nd]) + gb[ns]+gb[nd]) - (dot(z[ps],z[pd]) + gb[ps]+gb[pd]) + 1, 0 )
// gb[u] = bias[nids[u]]
// ---------------------------------------------------------------------------
__global__ __launch_bounds__(256)
void score_kernel(const float* __restrict__ z, const float* __restrict__ bias,
                  const int* __restrict__ nids,
                  const int* __restrict__ ps, const int* __restrict__ pd,
                  const int* __restrict__ ns, const int* __restrict__ nd,
                  float* __restrict__ out)
{
    __shared__ float sm[8];
    const int p = blockIdx.x, t = threadIdx.x;
    const int a = ps[p], b = pd[p], c = ns[p], d2 = nd[p];
    float vp = z[(size_t)a * HDIM + t] * z[(size_t)b * HDIM + t];
    float vn = z[(size_t)c * HDIM + t] * z[(size_t)d2 * HDIM + t];
#pragma unroll
    for (int off = 32; off > 0; off >>= 1) {
        vp += __shfl_down(vp, off);
        vn += __shfl_down(vn, off);
    }
    if ((t & 63) == 0) { sm[t >> 6] = vp; sm[4 + (t >> 6)] = vn; }
    __syncthreads();
    if (t == 0) {
        const float pos = sm[0] + sm[1] + sm[2] + sm[3]
                        + bias[nids[a]] + bias[nids[b]];
        const float neg = sm[4] + sm[5] + sm[6] + sm[7]
                        + bias[nids[c]] + bias[nids[d2]];
        out[p] = fmaxf(neg - pos + 1.0f, 0.f);
    }
}

// ---------------------------------------------------------------------------
extern "C" void kernel_launch(void* const* d_in, const int* in_sizes, int n_in,
                              void* d_out, int out_size, void* d_ws, size_t ws_size,
                              hipStream_t stream)
{
    const float* feat = (const float*)d_in[0];
    const float* Wp   = (const float*)d_in[1];
    const float* bp   = (const float*)d_in[2];
    const float* Q1   = (const float*)d_in[3];
    const float* bq1  = (const float*)d_in[4];
    const float* W1   = (const float*)d_in[5];
    const float* bw1  = (const float*)d_in[6];
    const float* Q2   = (const float*)d_in[7];
    const float* bq2  = (const float*)d_in[8];
    const float* W2   = (const float*)d_in[9];
    const float* bw2  = (const float*)d_in[10];
    const float* w1   = (const float*)d_in[11];
    const float* w2   = (const float*)d_in[12];
    const float* bias = (const float*)d_in[13];
    const int* src1   = (const int*)d_in[14];
    const int* dst1   = (const int*)d_in[15];
    const int* src2   = (const int*)d_in[16];
    const int* dst2   = (const int*)d_in[17];
    const int* pos_src = (const int*)d_in[18];
    const int* pos_dst = (const int*)d_in[19];
    const int* neg_src = (const int*)d_in[20];
    const int* neg_dst = (const int*)d_in[21];
    const int* nids    = (const int*)d_in[22];

    // workspace layout (fp32 elements), with reuse:
    //   hp   [N_SRC,H]                134.2 MB
    //   n1   [N_SRC,H]  (later n2)    134.2 MB
    //   aggn [N_MID,H]  (later agg2)   33.6 MB
    //   h1   [N_MID,H]  (t1 in place)  33.6 MB
    //   h2   [N_DST,H]  (t2 in place)   8.4 MB
    //   z    [N_DST,H]                  8.4 MB
    //   + int CSR arrays                ~3 MB
    float* ws   = (float*)d_ws;
    float* hp   = ws;
    float* n1   = hp   + (size_t)N_SRC * HDIM;
    float* aggn = n1   + (size_t)N_SRC * HDIM;
    float* h1   = aggn + (size_t)N_MID * HDIM;
    float* h2   = h1   + (size_t)N_MID * HDIM;
    float* zb   = h2   + (size_t)N_DST * HDIM;
    int* counts1 = (int*)(zb + (size_t)N_DST * HDIM);
    int* rs1     = counts1 + N_MID;
    int* cur1    = rs1 + N_MID + 1;
    int* el1     = cur1 + N_MID;
    int* counts2 = el1 + E1;
    int* rs2     = counts2 + N_DST;
    int* cur2    = rs2 + N_DST + 1;
    int* el2     = cur2 + N_DST;

    hipMemsetAsync(counts1, 0, N_MID * sizeof(int), stream);
    hipMemsetAsync(counts2, 0, N_DST * sizeof(int), stream);

    const dim3 blk(256);

    // hp = feat @ Wp^T + bp
    gemm_tn<0,0,1><<<dim3(N_SRC/128, 2), blk, 0, stream>>>(feat, HDIM, Wp, HDIM, bp, hp, HDIM, HDIM);
    // n1 = relu(hp @ Q1^T + bq1)
    gemm_tn<1,0,1><<<dim3(N_SRC/128, 2), blk, 0, stream>>>(hp, HDIM, Q1, HDIM, bq1, n1, HDIM, HDIM);

    // conv1 aggregation (CSR counting sort, then per-dst gather-accumulate)
    edge_count<<<1024, blk, 0, stream>>>(dst1, E1, counts1);
    scan_kernel<<<1, 1024, 0, stream>>>(counts1, N_MID, rs1, cur1);
    edge_fill<<<1024, blk, 0, stream>>>(dst1, E1, cur1, el1);
    aggregate<<<N_MID, blk, 0, stream>>>(n1, src1, w1, rs1, el1, aggn);

    // h1 = relu( aggn @ W1a^T + hp[:N_MID] @ W1b^T + bw1 )  (concat-GEMM split)
    gemm_tn<0,0,0><<<dim3(N_MID/128, 2), blk, 0, stream>>>(aggn, HDIM, W1, 2*HDIM, nullptr, h1, HDIM, HDIM);
    gemm_tn<1,1,1><<<dim3(N_MID/128, 2), blk, 0, stream>>>(hp, HDIM, W1 + HDIM, 2*HDIM, bw1, h1, HDIM, HDIM);

    // n2 = relu(h1 @ Q2^T + bq2)   (reuses n1 buffer)
    gemm_tn<1,0,1><<<dim3(N_MID/128, 2), blk, 0, stream>>>(h1, HDIM, Q2, HDIM, bq2, n1, HDIM, HDIM);

    // conv2 aggregation
    edge_count<<<512, blk, 0, stream>>>(dst2, E2, counts2);
    scan_kernel<<<1, 1024, 0, stream>>>(counts2, N_DST, rs2, cur2);
    edge_fill<<<512, blk, 0, stream>>>(dst2, E2, cur2, el2);
    aggregate<<<N_DST, blk, 0, stream>>>(n1, src2, w2, rs2, el2, aggn);

    // h2 = relu( aggn @ W2a^T + h1[:N_DST] @ W2b^T + bw2 )
    gemm_tn<0,0,0><<<dim3(N_DST/128, 2), blk, 0, stream>>>(aggn, HDIM, W2, 2*HDIM, nullptr, h2, HDIM, HDIM);
    gemm_tn<1,1,1><<<dim3(N_DST/128, 2), blk, 0, stream>>>(h1, HDIM, W2 + HDIM, 2*HDIM, bw2, h2, HDIM, HDIM);

    // z = normalize(hp[:N_DST] + h2); scores
    skip_norm<<<N_DST, blk, 0, stream>>>(hp, h2, zb);
    score_kernel<<<N_PAIRS, blk, 0, stream>>>(zb, bias, nids,
                                              pos_src, pos_dst, neg_src, neg_dst,
                                              (float*)d_out);
}

// Round 2
// 456.515 us; speedup vs baseline: 2.3359x; 2.3359x over previous
//
#include <hip/hip_runtime.h>

#define HDIM 256
constexpr int N_SRC = 131072, N_MID = 32768, N_DST = 8192;
constexpr int E1 = 524288, E2 = 131072;
constexpr int N_PAIRS = 8192;

typedef __attribute__((ext_vector_type(8))) short bf16x8;
typedef __attribute__((ext_vector_type(4))) float f32x4;

__device__ __forceinline__ float bf2f(unsigned short u) {
    return __uint_as_float(((unsigned int)u) << 16);
}
__device__ __forceinline__ unsigned short f2bf(float f) {
    unsigned int x = __float_as_uint(f);
    x += 0x7fff + ((x >> 16) & 1);          // round-to-nearest-even
    return (unsigned short)(x >> 16);
}

// ---------------------------------------------------------------------------
// bf16 MFMA GEMM: C[M,256] = act( A @ W^T + bias ),  A = [A0 | A1] (K=256 each)
// A0/A1: [M,256] fp32 (AT=float, converted in staging) or bf16 (AT=ushort).
// W: [256][NSRC*256] bf16. Tile 128x128, BK=64, 256 threads (4 waves),
// each wave computes 64x64 via 4x4 fragments of mfma_f32_16x16x32_bf16.
// LDS rows padded +8 bf16 (16B) -> uniform bank sweep on ds_read_b128.
// ---------------------------------------------------------------------------
template<typename AT, int NSRC, int ACT>
__global__ __launch_bounds__(256)
void gemm_mfma(const AT* __restrict__ A0, const AT* __restrict__ A1,
               const unsigned short* __restrict__ W,
               const float* __restrict__ bias,
               unsigned short* __restrict__ C)
{
    __shared__ unsigned short As[128][72];
    __shared__ unsigned short Ws[128][72];
    const int bm = blockIdx.x * 128;
    const int bn = blockIdx.y * 128;
    const int t  = threadIdx.x;
    const int g  = t >> 4;        // 0..15 staging row group
    const int lg = t & 15;        // 0..15 staging col group
    const int lane = t & 63;
    const int w  = t >> 6;        // wave 0..3
    const int wr = w >> 1, wc = w & 1;
    const int WLD = NSRC * 256;

    f32x4 acc[4][4];
#pragma unroll
    for (int m = 0; m < 4; ++m)
#pragma unroll
        for (int n = 0; n < 4; ++n) acc[m][n] = (f32x4){0.f, 0.f, 0.f, 0.f};

    for (int ks = 0; ks < NSRC * 4; ++ks) {
        const AT* Asrc = (NSRC == 2 && ks >= 4) ? A1 : A0;
        const int ka = (ks & 3) * 64;   // K offset within source
        const int kw = ks * 64;         // K offset within W
        // ---- stage A (128x64) and W (128x64) into LDS ----
#pragma unroll
        for (int i = 0; i < 8; ++i) {
            const int row = i * 16 + g;
            if constexpr (sizeof(AT) == 4) {
                const float4 v = *reinterpret_cast<const float4*>(
                    &Asrc[(size_t)(bm + row) * 256 + ka + lg * 4]);
                ushort4 o;
                o.x = f2bf(v.x); o.y = f2bf(v.y); o.z = f2bf(v.z); o.w = f2bf(v.w);
                *reinterpret_cast<ushort4*>(&As[row][lg * 4]) = o;
            } else {
                *reinterpret_cast<ushort4*>(&As[row][lg * 4]) =
                    *reinterpret_cast<const ushort4*>(
                        &Asrc[(size_t)(bm + row) * 256 + ka + lg * 4]);
            }
            *reinterpret_cast<ushort4*>(&Ws[row][lg * 4]) =
                *reinterpret_cast<const ushort4*>(
                    &W[(size_t)(bn + row) * WLD + kw + lg * 4]);
        }
        __syncthreads();
        // ---- MFMA: 2 k-slices x 4x4 fragments ----
        const int kcol = (lane >> 4) * 8;
        const int ar = wr * 64 + (lane & 15);
        const int br = wc * 64 + (lane & 15);
#pragma unroll
        for (int kk = 0; kk < 2; ++kk) {
            bf16x8 af[4], bf[4];
#pragma unroll
            for (int m = 0; m < 4; ++m)
                af[m] = *reinterpret_cast<const bf16x8*>(&As[ar + m * 16][kk * 32 + kcol]);
#pragma unroll
            for (int n = 0; n < 4; ++n)
                bf[n] = *reinterpret_cast<const bf16x8*>(&Ws[br + n * 16][kk * 32 + kcol]);
#pragma unroll
            for (int m = 0; m < 4; ++m)
#pragma unroll
                for (int n = 0; n < 4; ++n)
                    acc[m][n] = __builtin_amdgcn_mfma_f32_16x16x32_bf16(
                        af[m], bf[n], acc[m][n], 0, 0, 0);
        }
        __syncthreads();
    }
    // ---- epilogue: bias + act + bf16 store ----
    const int rb = (lane >> 4) * 4;
#pragma unroll
    for (int n = 0; n < 4; ++n) {
        const int col = bn + wc * 64 + n * 16 + (lane & 15);
        const float bv = bias[col];
#pragma unroll
        for (int m = 0; m < 4; ++m) {
            const int row0 = bm + wr * 64 + m * 16 + rb;
#pragma unroll
            for (int j = 0; j < 4; ++j) {
                float v = acc[m][n][j] + bv;
                if (ACT) v = fmaxf(v, 0.f);
                C[(size_t)(row0 + j) * 256 + col] = f2bf(v);
            }
        }
    }
}

// ---------------------------------------------------------------------------
// Convert the 5 weight matrices fp32 -> bf16 (one kernel)
// layout: [Wp 65536][Q1 65536][W1 131072][Q2 65536][W2 131072]
// ---------------------------------------------------------------------------
__global__ __launch_bounds__(256)
void conv_w(const float* __restrict__ Wp, const float* __restrict__ Q1,
            const float* __restrict__ W1, const float* __restrict__ Q2,
            const float* __restrict__ W2, unsigned short* __restrict__ out)
{
    const int i = blockIdx.x * 256 + threadIdx.x;
    const float* src; int off;
    if (i < 65536)       { src = Wp; off = i; }
    else if (i < 131072) { src = Q1; off = i - 65536; }
    else if (i < 262144) { src = W1; off = i - 131072; }
    else if (i < 327680) { src = Q2; off = i - 262144; }
    else                 { src = W2; off = i - 327680; }
    out[i] = f2bf(src[off]);
}

// ---------------------------------------------------------------------------
// CSR build: count -> scan -> fill
// ---------------------------------------------------------------------------
__global__ void edge_count(const int* __restrict__ dst, int E, int* __restrict__ counts)
{
    int i = blockIdx.x * blockDim.x + threadIdx.x;
    const int stride = gridDim.x * blockDim.x;
    for (; i < E; i += stride) atomicAdd(&counts[dst[i]], 1);
}

__global__ __launch_bounds__(1024)
void scan_kernel(const int* __restrict__ counts, int n,
                 int* __restrict__ row_start, int* __restrict__ cursor)
{
    __shared__ int part[1024];
    const int t = threadIdx.x;
    const int per = n >> 10;
    const int base = t * per;
    int s = 0;
    for (int j = 0; j < per; ++j) s += counts[base + j];
    part[t] = s;
    __syncthreads();
    for (int off = 1; off < 1024; off <<= 1) {
        int v = (t >= off) ? part[t - off] : 0;
        __syncthreads();
        part[t] += v;
        __syncthreads();
    }
    int run = (t == 0) ? 0 : part[t - 1];
    for (int j = 0; j < per; ++j) {
        row_start[base + j] = run;
        cursor[base + j] = run;
        run += counts[base + j];
    }
    if (t == 1023) row_start[n] = run;
}

__global__ void edge_fill(const int* __restrict__ dst, int E,
                          int* __restrict__ cursor, int* __restrict__ elist)
{
    int i = blockIdx.x * blockDim.x + threadIdx.x;
    const int stride = gridDim.x * blockDim.x;
    for (; i < E; i += stride) {
        const int p = atomicAdd(&cursor[dst[i]], 1);
        elist[p] = i;
    }
}

// ---------------------------------------------------------------------------
// Weighted aggregate: one wave per dst row, 4 dst/block, ushort4 (8B) lanes.
// agg[d] = (sum_e w_e * n[src_e]) / max(sum_e w_e, 1)   (bf16 in/out, fp32 acc)
// ---------------------------------------------------------------------------
__global__ __launch_bounds__(256)
void aggregate(const unsigned short* __restrict__ nsrc, const int* __restrict__ src,
               const float* __restrict__ w, const int* __restrict__ rs,
               const int* __restrict__ el, unsigned short* __restrict__ agg)
{
    const int d = blockIdx.x * 4 + (threadIdx.x >> 6);
    const int lane = threadIdx.x & 63;
    const int p0 = rs[d], p1 = rs[d + 1];
    float a0 = 0.f, a1 = 0.f, a2 = 0.f, a3 = 0.f, wsum = 0.f;
    for (int p = p0; p < p1; ++p) {
        const int e = el[p];
        const float wt = w[e];
        const int s = src[e];
        const ushort4 v = *reinterpret_cast<const ushort4*>(&nsrc[(size_t)s * 256 + lane * 4]);
        a0 += bf2f(v.x) * wt; a1 += bf2f(v.y) * wt;
        a2 += bf2f(v.z) * wt; a3 += bf2f(v.w) * wt;
        wsum += wt;
    }
    const float inv = 1.f / fmaxf(wsum, 1.f);
    ushort4 o;
    o.x = f2bf(a0 * inv); o.y = f2bf(a1 * inv);
    o.z = f2bf(a2 * inv); o.w = f2bf(a3 * inv);
    *reinterpret_cast<ushort4*>(&agg[(size_t)d * 256 + lane * 4]) = o;
}

// ---------------------------------------------------------------------------
// z = normalize(hp[:N_DST] + h2)   (bf16 in, fp32 out)
// ---------------------------------------------------------------------------
__global__ __launch_bounds__(256)
void skip_norm(const unsigned short* __restrict__ hp, const unsigned short* __restrict__ h2,
               float* __restrict__ z)
{
    __shared__ float sm[4];
    const int d = blockIdx.x, t = threadIdx.x;
    const float v = bf2f(hp[(size_t)d * 256 + t]) + bf2f(h2[(size_t)d * 256 + t]);
    float s = v * v;
#pragma unroll
    for (int off = 32; off > 0; off >>= 1) s += __shfl_down(s, off);
    if ((t & 63) == 0) sm[t >> 6] = s;
    __syncthreads();
    const float tot = sm[0] + sm[1] + sm[2] + sm[3];
    const float nrm = sqrtf(tot);
    const float inv = (nrm == 0.f) ? 1.f : 1.f / nrm;
    z[(size_t)d * 256 + t] = v * inv;
}

// ---------------------------------------------------------------------------
__global__ __launch_bounds__(256)
void score_kernel(const float* __restrict__ z, const float* __restrict__ bias,
                  const int* __restrict__ nids,
                  const int* __restrict__ ps, const int* __restrict__ pd,
                  const int* __restrict__ ns, const int* __restrict__ nd,
                  float* __restrict__ out)
{
    __shared__ float sm[8];
    const int p = blockIdx.x, t = threadIdx.x;
    const int a = ps[p], b = pd[p], c = ns[p], d2 = nd[p];
    float vp = z[(size_t)a * 256 + t] * z[(size_t)b * 256 + t];
    float vn = z[(size_t)c * 256 + t] * z[(size_t)d2 * 256 + t];
#pragma unroll
    for (int off = 32; off > 0; off >>= 1) {
        vp += __shfl_down(vp, off);
        vn += __shfl_down(vn, off);
    }
    if ((t & 63) == 0) { sm[t >> 6] = vp; sm[4 + (t >> 6)] = vn; }
    __syncthreads();
    if (t == 0) {
        const float pos = sm[0] + sm[1] + sm[2] + sm[3] + bias[nids[a]] + bias[nids[b]];
        const float neg = sm[4] + sm[5] + sm[6] + sm[7] + bias[nids[c]] + bias[nids[d2]];
        out[p] = fmaxf(neg - pos + 1.0f, 0.f);
    }
}

// ---------------------------------------------------------------------------
extern "C" void kernel_launch(void* const* d_in, const int* in_sizes, int n_in,
                              void* d_out, int out_size, void* d_ws, size_t ws_size,
                              hipStream_t stream)
{
    const float* feat = (const float*)d_in[0];
    const float* Wp   = (const float*)d_in[1];
    const float* bp   = (const float*)d_in[2];
    const float* Q1   = (const float*)d_in[3];
    const float* bq1  = (const float*)d_in[4];
    const float* W1   = (const float*)d_in[5];
    const float* bw1  = (const float*)d_in[6];
    const float* Q2   = (const float*)d_in[7];
    const float* bq2  = (const float*)d_in[8];
    const float* W2   = (const float*)d_in[9];
    const float* bw2  = (const float*)d_in[10];
    const float* w1   = (const float*)d_in[11];
    const float* w2   = (const float*)d_in[12];
    const float* bias = (const float*)d_in[13];
    const int* src1   = (const int*)d_in[14];
    const int* dst1   = (const int*)d_in[15];
    const int* src2   = (const int*)d_in[16];
    const int* dst2   = (const int*)d_in[17];
    const int* pos_src = (const int*)d_in[18];
    const int* pos_dst = (const int*)d_in[19];
    const int* neg_src = (const int*)d_in[20];
    const int* neg_dst = (const int*)d_in[21];
    const int* nids    = (const int*)d_in[22];

    // workspace layout (bf16 intermediates), ~184 MB total
    unsigned short* hp   = (unsigned short*)d_ws;              // [N_SRC,256]
    unsigned short* n1   = hp   + (size_t)N_SRC * 256;         // [N_SRC,256] (reused as n2)
    unsigned short* aggb = n1   + (size_t)N_SRC * 256;         // [N_MID,256] (reused as agg2)
    unsigned short* h1   = aggb + (size_t)N_MID * 256;         // [N_MID,256]
    unsigned short* h2   = h1   + (size_t)N_MID * 256;         // [N_DST,256]
    unsigned short* wb   = h2   + (size_t)N_DST * 256;         // 458752 bf16 weights
    float* zb            = (float*)(wb + 458752);              // [N_DST,256] fp32
    int* counts1 = (int*)(zb + (size_t)N_DST * 256);
    int* rs1     = counts1 + N_MID;
    int* cur1    = rs1 + N_MID + 1;
    int* el1     = cur1 + N_MID;
    int* counts2 = el1 + E1;
    int* rs2     = counts2 + N_DST;
    int* cur2    = rs2 + N_DST + 1;
    int* el2     = cur2 + N_DST;

    const unsigned short* Wpb = wb;
    const unsigned short* Q1b = wb + 65536;
    const unsigned short* W1b = wb + 131072;
    const unsigned short* Q2b = wb + 262144;
    const unsigned short* W2b = wb + 327680;

    hipMemsetAsync(counts1, 0, N_MID * sizeof(int), stream);
    hipMemsetAsync(counts2, 0, N_DST * sizeof(int), stream);

    const dim3 blk(256);
    conv_w<<<1792, blk, 0, stream>>>(Wp, Q1, W1, Q2, W2, wb);

    // hp = feat @ Wp^T + bp   (fp32 A, converted in staging)
    gemm_mfma<float, 1, 0><<<dim3(N_SRC / 128, 2), blk, 0, stream>>>(
        feat, (const float*)nullptr, Wpb, bp, hp);
    // n1 = relu(hp @ Q1^T + bq1)
    gemm_mfma<unsigned short, 1, 1><<<dim3(N_SRC / 128, 2), blk, 0, stream>>>(
        hp, (const unsigned short*)nullptr, Q1b, bq1, n1);

    // conv1 aggregation
    edge_count<<<1024, blk, 0, stream>>>(dst1, E1, counts1);
    scan_kernel<<<1, 1024, 0, stream>>>(counts1, N_MID, rs1, cur1);
    edge_fill<<<1024, blk, 0, stream>>>(dst1, E1, cur1, el1);
    aggregate<<<N_MID / 4, blk, 0, stream>>>(n1, src1, w1, rs1, el1, aggb);

    // h1 = relu( [agg1 | hp[:N_MID]] @ W1^T + bw1 )   (fused K=512)
    gemm_mfma<unsigned short, 2, 1><<<dim3(N_MID / 128, 2), blk, 0, stream>>>(
        aggb, hp, W1b, bw1, h1);

    // n2 = relu(h1 @ Q2^T + bq2)   (into n1 buffer)
    gemm_mfma<unsigned short, 1, 1><<<dim3(N_MID / 128, 2), blk, 0, stream>>>(
        h1, (const unsigned short*)nullptr, Q2b, bq2, n1);

    // conv2 aggregation
    edge_count<<<512, blk, 0, stream>>>(dst2, E2, counts2);
    scan_kernel<<<1, 1024, 0, stream>>>(counts2, N_DST, rs2, cur2);
    edge_fill<<<512, blk, 0, stream>>>(dst2, E2, cur2, el2);
    aggregate<<<N_DST / 4, blk, 0, stream>>>(n1, src2, w2, rs2, el2, aggb);

    // h2 = relu( [agg2 | h1[:N_DST]] @ W2^T + bw2 )
    gemm_mfma<unsigned short, 2, 1><<<dim3(N_DST / 128, 2), blk, 0, stream>>>(
        aggb, h1, W2b, bw2, h2);

    // z = normalize(hp[:N_DST] + h2); scores
    skip_norm<<<N_DST, blk, 0, stream>>>(hp, h2, zb);
    score_kernel<<<N_PAIRS, blk, 0, stream>>>(zb, bias, nids,
                                              pos_src, pos_dst, neg_src, neg_dst,
                                              (float*)d_out);
}

// Round 3
// 402.792 us; speedup vs baseline: 2.6475x; 1.1334x over previous
//
#include <hip/hip_runtime.h>

#define HDIM 256
constexpr int N_SRC = 131072, N_MID = 32768, N_DST = 8192;
constexpr int E1 = 524288, E2 = 131072;
constexpr int N_PAIRS = 8192;

typedef __attribute__((ext_vector_type(8))) short bf16x8;
typedef __attribute__((ext_vector_type(4))) float f32x4;

__device__ __forceinline__ float bf2f(unsigned short u) {
    return __uint_as_float(((unsigned int)u) << 16);
}
__device__ __forceinline__ unsigned short f2bf(float f) {
    unsigned int x = __float_as_uint(f);
    x += 0x7fff + ((x >> 16) & 1);          // round-to-nearest-even
    return (unsigned short)(x >> 16);
}

// ---------------------------------------------------------------------------
// bf16 MFMA GEMM: C[M,256] = act( A @ W^T + bias ),  A = [A0 | A1] (K=256 each)
// A0/A1: [M,256] fp32 (AT=float, converted in staging) or bf16 (AT=ushort).
// W: [256][NSRC*256] bf16. Tile 128x128, BK=64, 256 threads (4 waves),
// each wave computes 64x64 via 4x4 fragments of mfma_f32_16x16x32_bf16.
// ---------------------------------------------------------------------------
template<typename AT, int NSRC, int ACT>
__global__ __launch_bounds__(256)
void gemm_mfma(const AT* __restrict__ A0, const AT* __restrict__ A1,
               const unsigned short* __restrict__ W,
               const float* __restrict__ bias,
               unsigned short* __restrict__ C)
{
    __shared__ unsigned short As[128][72];
    __shared__ unsigned short Ws[128][72];
    const int bm = blockIdx.x * 128;
    const int bn = blockIdx.y * 128;
    const int t  = threadIdx.x;
    const int g  = t >> 4;        // 0..15 staging row group
    const int lg = t & 15;        // 0..15 staging col group
    const int lane = t & 63;
    const int w  = t >> 6;        // wave 0..3
    const int wr = w >> 1, wc = w & 1;
    const int WLD = NSRC * 256;

    f32x4 acc[4][4];
#pragma unroll
    for (int m = 0; m < 4; ++m)
#pragma unroll
        for (int n = 0; n < 4; ++n) acc[m][n] = (f32x4){0.f, 0.f, 0.f, 0.f};

    for (int ks = 0; ks < NSRC * 4; ++ks) {
        const AT* Asrc = (NSRC == 2 && ks >= 4) ? A1 : A0;
        const int ka = (ks & 3) * 64;   // K offset within source
        const int kw = ks * 64;         // K offset within W
#pragma unroll
        for (int i = 0; i < 8; ++i) {
            const int row = i * 16 + g;
            if constexpr (sizeof(AT) == 4) {
                const float4 v = *reinterpret_cast<const float4*>(
                    &Asrc[(size_t)(bm + row) * 256 + ka + lg * 4]);
                ushort4 o;
                o.x = f2bf(v.x); o.y = f2bf(v.y); o.z = f2bf(v.z); o.w = f2bf(v.w);
                *reinterpret_cast<ushort4*>(&As[row][lg * 4]) = o;
            } else {
                *reinterpret_cast<ushort4*>(&As[row][lg * 4]) =
                    *reinterpret_cast<const ushort4*>(
                        &Asrc[(size_t)(bm + row) * 256 + ka + lg * 4]);
            }
            *reinterpret_cast<ushort4*>(&Ws[row][lg * 4]) =
                *reinterpret_cast<const ushort4*>(
                    &W[(size_t)(bn + row) * WLD + kw + lg * 4]);
        }
        __syncthreads();
        const int kcol = (lane >> 4) * 8;
        const int ar = wr * 64 + (lane & 15);
        const int br = wc * 64 + (lane & 15);
#pragma unroll
        for (int kk = 0; kk < 2; ++kk) {
            bf16x8 af[4], bfr[4];
#pragma unroll
            for (int m = 0; m < 4; ++m)
                af[m] = *reinterpret_cast<const bf16x8*>(&As[ar + m * 16][kk * 32 + kcol]);
#pragma unroll
            for (int n = 0; n < 4; ++n)
                bfr[n] = *reinterpret_cast<const bf16x8*>(&Ws[br + n * 16][kk * 32 + kcol]);
#pragma unroll
            for (int m = 0; m < 4; ++m)
#pragma unroll
                for (int n = 0; n < 4; ++n)
                    acc[m][n] = __builtin_amdgcn_mfma_f32_16x16x32_bf16(
                        af[m], bfr[n], acc[m][n], 0, 0, 0);
        }
        __syncthreads();
    }
    const int rb = (lane >> 4) * 4;
#pragma unroll
    for (int n = 0; n < 4; ++n) {
        const int col = bn + wc * 64 + n * 16 + (lane & 15);
        const float bv = bias[col];
#pragma unroll
        for (int m = 0; m < 4; ++m) {
            const int row0 = bm + wr * 64 + m * 16 + rb;
#pragma unroll
            for (int j = 0; j < 4; ++j) {
                float v = acc[m][n][j] + bv;
                if (ACT) v = fmaxf(v, 0.f);
                C[(size_t)(row0 + j) * 256 + col] = f2bf(v);
            }
        }
    }
}

// ---------------------------------------------------------------------------
// Convert the 5 weight matrices fp32 -> bf16
// ---------------------------------------------------------------------------
__global__ __launch_bounds__(256)
void conv_w(const float* __restrict__ Wp, const float* __restrict__ Q1,
            const float* __restrict__ W1, const float* __restrict__ Q2,
            const float* __restrict__ W2, unsigned short* __restrict__ out)
{
    const int i = blockIdx.x * 256 + threadIdx.x;
    const float* src; int off;
    if (i < 65536)       { src = Wp; off = i; }
    else if (i < 131072) { src = Q1; off = i - 65536; }
    else if (i < 262144) { src = W1; off = i - 131072; }
    else if (i < 327680) { src = Q2; off = i - 262144; }
    else                 { src = W2; off = i - 327680; }
    out[i] = f2bf(src[off]);
}

// ---------------------------------------------------------------------------
// CSR build: count -> scan -> fill (fill scatters src & w into CSR order)
// ---------------------------------------------------------------------------
__global__ void edge_count(const int* __restrict__ dst, int E, int* __restrict__ counts)
{
    int i = blockIdx.x * blockDim.x + threadIdx.x;
    const int stride = gridDim.x * blockDim.x;
    for (; i < E; i += stride) atomicAdd(&counts[dst[i]], 1);
}

__global__ __launch_bounds__(1024)
void scan_kernel(const int* __restrict__ counts, int n,
                 int* __restrict__ row_start, int* __restrict__ cursor)
{
    __shared__ int part[1024];
    const int t = threadIdx.x;
    const int per = n >> 10;
    const int base = t * per;
    int s = 0;
    for (int j = 0; j < per; ++j) s += counts[base + j];
    part[t] = s;
    __syncthreads();
    for (int off = 1; off < 1024; off <<= 1) {
        int v = (t >= off) ? part[t - off] : 0;
        __syncthreads();
        part[t] += v;
        __syncthreads();
    }
    int run = (t == 0) ? 0 : part[t - 1];
    for (int j = 0; j < per; ++j) {
        row_start[base + j] = run;
        cursor[base + j] = run;
        run += counts[base + j];
    }
    if (t == 1023) row_start[n] = run;
}

__global__ void edge_fill(const int* __restrict__ dst, const int* __restrict__ src,
                          const float* __restrict__ w, int E,
                          int* __restrict__ cursor,
                          int* __restrict__ ssrc, float* __restrict__ sw)
{
    int i = blockIdx.x * blockDim.x + threadIdx.x;
    const int stride = gridDim.x * blockDim.x;
    for (; i < E; i += stride) {
        const int p = atomicAdd(&cursor[dst[i]], 1);
        ssrc[p] = src[i];
        sw[p]   = w[i];
    }
}

// ---------------------------------------------------------------------------
// Weighted aggregate with 4x memory-level parallelism.
// One wave per dst row (4 dst/block). Edge records (src,w) preloaded into
// per-lane registers, shfl-broadcast; gather loop unrolled x4 so 4
// independent 8B row-gathers are in flight. Each wave-load = 1 full 512B row.
// ---------------------------------------------------------------------------
__global__ __launch_bounds__(256)
void aggregate(const unsigned short* __restrict__ nsrc,
               const int* __restrict__ ssrc, const float* __restrict__ sw,
               const int* __restrict__ rs, unsigned short* __restrict__ agg)
{
    const int d = blockIdx.x * 4 + (threadIdx.x >> 6);
    const int lane = threadIdx.x & 63;
    const int p0 = rs[d], p1 = rs[d + 1];
    float a0 = 0.f, a1 = 0.f, a2 = 0.f, a3 = 0.f, wacc = 0.f;

    for (int base = p0; base < p1; base += 64) {
        const int cnt = min(64, p1 - base);
        int   mySrc = 0;
        float myW   = 0.f;
        if (lane < cnt) { mySrc = ssrc[base + lane]; myW = sw[base + lane]; }
        wacc += myW;
        int j = 0;
        for (; j + 4 <= cnt; j += 4) {
            const int   s0 = __shfl(mySrc, j + 0), s1 = __shfl(mySrc, j + 1);
            const int   s2 = __shfl(mySrc, j + 2), s3 = __shfl(mySrc, j + 3);
            const float w0 = __shfl(myW, j + 0),   w1 = __shfl(myW, j + 1);
            const float w2 = __shfl(myW, j + 2),   w3 = __shfl(myW, j + 3);
            const ushort4 r0 = *reinterpret_cast<const ushort4*>(&nsrc[(size_t)s0 * 256 + lane * 4]);
            const ushort4 r1 = *reinterpret_cast<const ushort4*>(&nsrc[(size_t)s1 * 256 + lane * 4]);
            const ushort4 r2 = *reinterpret_cast<const ushort4*>(&nsrc[(size_t)s2 * 256 + lane * 4]);
            const ushort4 r3 = *reinterpret_cast<const ushort4*>(&nsrc[(size_t)s3 * 256 + lane * 4]);
            a0 += bf2f(r0.x) * w0; a1 += bf2f(r0.y) * w0; a2 += bf2f(r0.z) * w0; a3 += bf2f(r0.w) * w0;
            a0 += bf2f(r1.x) * w1; a1 += bf2f(r1.y) * w1; a2 += bf2f(r1.z) * w1; a3 += bf2f(r1.w) * w1;
            a0 += bf2f(r2.x) * w2; a1 += bf2f(r2.y) * w2; a2 += bf2f(r2.z) * w2; a3 += bf2f(r2.w) * w2;
            a0 += bf2f(r3.x) * w3; a1 += bf2f(r3.y) * w3; a2 += bf2f(r3.z) * w3; a3 += bf2f(r3.w) * w3;
        }
        for (; j < cnt; ++j) {
            const int   s = __shfl(mySrc, j);
            const float wj = __shfl(myW, j);
            const ushort4 r = *reinterpret_cast<const ushort4*>(&nsrc[(size_t)s * 256 + lane * 4]);
            a0 += bf2f(r.x) * wj; a1 += bf2f(r.y) * wj; a2 += bf2f(r.z) * wj; a3 += bf2f(r.w) * wj;
        }
    }
    float ws = wacc;
#pragma unroll
    for (int off = 32; off > 0; off >>= 1) ws += __shfl_xor(ws, off);
    const float inv = 1.f / fmaxf(ws, 1.f);
    ushort4 o;
    o.x = f2bf(a0 * inv); o.y = f2bf(a1 * inv);
    o.z = f2bf(a2 * inv); o.w = f2bf(a3 * inv);
    *reinterpret_cast<ushort4*>(&agg[(size_t)d * 256 + lane * 4]) = o;
}

// ---------------------------------------------------------------------------
// z = normalize(hp[:N_DST] + h2)   (bf16 in, fp32 out)
// ---------------------------------------------------------------------------
__global__ __launch_bounds__(256)
void skip_norm(const unsigned short* __restrict__ hp, const unsigned short* __restrict__ h2,
               float* __restrict__ z)
{
    __shared__ float sm[4];
    const int d = blockIdx.x, t = threadIdx.x;
    const float v = bf2f(hp[(size_t)d * 256 + t]) + bf2f(h2[(size_t)d * 256 + t]);
    float s = v * v;
#pragma unroll
    for (int off = 32; off > 0; off >>= 1) s += __shfl_down(s, off);
    if ((t & 63) == 0) sm[t >> 6] = s;
    __syncthreads();
    const float tot = sm[0] + sm[1] + sm[2] + sm[3];
    const float nrm = sqrtf(tot);
    const float inv = (nrm == 0.f) ? 1.f : 1.f / nrm;
    z[(size_t)d * 256 + t] = v * inv;
}

// ---------------------------------------------------------------------------
__global__ __launch_bounds__(256)
void score_kernel(const float* __restrict__ z, const float* __restrict__ bias,
                  const int* __restrict__ nids,
                  const int* __restrict__ ps, const int* __restrict__ pd,
                  const int* __restrict__ ns, const int* __restrict__ nd,
                  float* __restrict__ out)
{
    __shared__ float sm[8];
    const int p = blockIdx.x, t = threadIdx.x;
    const int a = ps[p], b = pd[p], c = ns[p], d2 = nd[p];
    float vp = z[(size_t)a * 256 + t] * z[(size_t)b * 256 + t];
    float vn = z[(size_t)c * 256 + t] * z[(size_t)d2 * 256 + t];
#pragma unroll
    for (int off = 32; off > 0; off >>= 1) {
        vp += __shfl_down(vp, off);
        vn += __shfl_down(vn, off);
    }
    if ((t & 63) == 0) { sm[t >> 6] = vp; sm[4 + (t >> 6)] = vn; }
    __syncthreads();
    if (t == 0) {
        const float pos = sm[0] + sm[1] + sm[2] + sm[3] + bias[nids[a]] + bias[nids[b]];
        const float neg = sm[4] + sm[5] + sm[6] + sm[7] + bias[nids[c]] + bias[nids[d2]];
        out[p] = fmaxf(neg - pos + 1.0f, 0.f);
    }
}

// ---------------------------------------------------------------------------
extern "C" void kernel_launch(void* const* d_in, const int* in_sizes, int n_in,
                              void* d_out, int out_size, void* d_ws, size_t ws_size,
                              hipStream_t stream)
{
    const float* feat = (const float*)d_in[0];
    const float* Wp   = (const float*)d_in[1];
    const float* bp   = (const float*)d_in[2];
    const float* Q1   = (const float*)d_in[3];
    const float* bq1  = (const float*)d_in[4];
    const float* W1   = (const float*)d_in[5];
    const float* bw1  = (const float*)d_in[6];
    const float* Q2   = (const float*)d_in[7];
    const float* bq2  = (const float*)d_in[8];
    const float* W2   = (const float*)d_in[9];
    const float* bw2  = (const float*)d_in[10];
    const float* w1   = (const float*)d_in[11];
    const float* w2   = (const float*)d_in[12];
    const float* bias = (const float*)d_in[13];
    const int* src1   = (const int*)d_in[14];
    const int* dst1   = (const int*)d_in[15];
    const int* src2   = (const int*)d_in[16];
    const int* dst2   = (const int*)d_in[17];
    const int* pos_src = (const int*)d_in[18];
    const int* pos_dst = (const int*)d_in[19];
    const int* neg_src = (const int*)d_in[20];
    const int* neg_dst = (const int*)d_in[21];
    const int* nids    = (const int*)d_in[22];

    // workspace layout (bf16 intermediates + CSR with scattered src/w)
    unsigned short* hp   = (unsigned short*)d_ws;              // [N_SRC,256]
    unsigned short* n1   = hp   + (size_t)N_SRC * 256;         // [N_SRC,256] (reused as n2)
    unsigned short* aggb = n1   + (size_t)N_SRC * 256;         // [N_MID,256] (reused as agg2)
    unsigned short* h1   = aggb + (size_t)N_MID * 256;         // [N_MID,256]
    unsigned short* h2   = h1   + (size_t)N_MID * 256;         // [N_DST,256]
    unsigned short* wb   = h2   + (size_t)N_DST * 256;         // 458752 bf16 weights
    float* zb            = (float*)(wb + 458752);              // [N_DST,256] fp32
    int* counts1 = (int*)(zb + (size_t)N_DST * 256);
    int* rs1     = counts1 + N_MID;
    int* cur1    = rs1 + N_MID + 1;
    int* ssrc1   = cur1 + N_MID;
    float* sw1   = (float*)(ssrc1 + E1);
    int* counts2 = (int*)(sw1 + E1);
    int* rs2     = counts2 + N_DST;
    int* cur2    = rs2 + N_DST + 1;
    int* ssrc2   = cur2 + N_DST;
    float* sw2   = (float*)(ssrc2 + E2);

    const unsigned short* Wpb = wb;
    const unsigned short* Q1b = wb + 65536;
    const unsigned short* W1b = wb + 131072;
    const unsigned short* Q2b = wb + 262144;
    const unsigned short* W2b = wb + 327680;

    hipMemsetAsync(counts1, 0, N_MID * sizeof(int), stream);
    hipMemsetAsync(counts2, 0, N_DST * sizeof(int), stream);

    const dim3 blk(256);
    conv_w<<<1792, blk, 0, stream>>>(Wp, Q1, W1, Q2, W2, wb);

    // hp = feat @ Wp^T + bp   (fp32 A, converted in staging)
    gemm_mfma<float, 1, 0><<<dim3(N_SRC / 128, 2), blk, 0, stream>>>(
        feat, (const float*)nullptr, Wpb, bp, hp);
    // n1 = relu(hp @ Q1^T + bq1)
    gemm_mfma<unsigned short, 1, 1><<<dim3(N_SRC / 128, 2), blk, 0, stream>>>(
        hp, (const unsigned short*)nullptr, Q1b, bq1, n1);

    // conv1 aggregation
    edge_count<<<1024, blk, 0, stream>>>(dst1, E1, counts1);
    scan_kernel<<<1, 1024, 0, stream>>>(counts1, N_MID, rs1, cur1);
    edge_fill<<<1024, blk, 0, stream>>>(dst1, src1, w1, E1, cur1, ssrc1, sw1);
    aggregate<<<N_MID / 4, blk, 0, stream>>>(n1, ssrc1, sw1, rs1, aggb);

    // h1 = relu( [agg1 | hp[:N_MID]] @ W1^T + bw1 )   (fused K=512)
    gemm_mfma<unsigned short, 2, 1><<<dim3(N_MID / 128, 2), blk, 0, stream>>>(
        aggb, hp, W1b, bw1, h1);

    // n2 = relu(h1 @ Q2^T + bq2)   (into n1 buffer)
    gemm_mfma<unsigned short, 1, 1><<<dim3(N_MID / 128, 2), blk, 0, stream>>>(
        h1, (const unsigned short*)nullptr, Q2b, bq2, n1);

    // conv2 aggregation
    edge_count<<<512, blk, 0, stream>>>(dst2, E2, counts2);
    scan_kernel<<<1, 1024, 0, stream>>>(counts2, N_DST, rs2, cur2);
    edge_fill<<<512, blk, 0, stream>>>(dst2, src2, w2, E2, cur2, ssrc2, sw2);
    aggregate<<<N_DST / 4, blk, 0, stream>>>(n1, ssrc2, sw2, rs2, aggb);

    // h2 = relu( [agg2 | h1[:N_DST]] @ W2^T + bw2 )
    gemm_mfma<unsigned short, 2, 1><<<dim3(N_DST / 128, 2), blk, 0, stream>>>(
        aggb, h1, W2b, bw2, h2);

    // z = normalize(hp[:N_DST] + h2); scores
    skip_norm<<<N_DST, blk, 0, stream>>>(hp, h2, zb);
    score_kernel<<<N_PAIRS, blk, 0, stream>>>(zb, bias, nids,
                                              pos_src, pos_dst, neg_src, neg_dst,
                                              (float*)d_out);
}